// Round 8
// baseline (259.302 us; speedup 1.0000x reference)
//
#include <hip/hip_runtime.h>

// Math (verified): softmax over a size-1 axis == 1, so
//   out = relu(x @ (gamma*W3 + W4)^T),  x:(B,20), fused M:(200,20)
// Memory floor: 210 MB out write + 21 MB x read => ~34-37 us.
//
// Ladder (kernel-only, dur - fill - 49): R0 row-lane stores ~116 ->
// R1 global-broadcast x 161 -> R2 LDS-x 50-lane ~88 -> v5 float2 ~79 ->
// v6 wave-row float4 + pipeline ~70. R6/R7: inline-asm s_load variant
// killed the container twice -> inline asm abandoned entirely.
//
// v8: same structural idea as v7 (x row is WAVE-UNIFORM -> SGPRs), but in
// pure C via the composable_kernel constant-address-space pattern:
//   - x pointer (readfirstlane-uniform) cast to addrspace(4); uniform
//     loads from AS(4) lower to s_load_dwordxN, values live in SGPRs and
//     feed v_fmac_f32 as the one legal scalar operand. No inline asm.
//   - deletes ALL LDS (no barrier, no ds_reads, no xv/xn VGPRs):
//     VGPR ~100 -> 5 waves/SIMD (was 3); TLP replaces hand pipelining.
//   - per row: ~3 merged s_loads + 80 FMAs + one contiguous 800 B
//     nontemporal store (2-row unroll -> 2 stores of vmcnt slack).
//   - M = g*W3+W4 fused from global (16 KB, L2-resident), kept from v5/v6.
//   - worst case (compiler declines to scalarize): loads stay VMEM,
//     kernel ~= v5-class, still correct -- zero crash risk.

#define BATCH          262144
#define DICT           20
#define COLS           200                        // NUM_HEADS * DICT
#define NTHREADS       256                        // 4 waves
#define ROWS_PER_BLOCK 128
#define ROWS_PER_WAVE  32
#define NBLOCKS        (BATCH / ROWS_PER_BLOCK)   // 2048

typedef float f32x4 __attribute__((ext_vector_type(4)));
// Constant-address-space float: uniform loads -> s_load (SGPR destination).
typedef const float __attribute__((address_space(4))) kfloat;

// dot(M[4cf4+c][:], xrow) for c=0..3 + ReLU. XS[] are wave-uniform scalars
// (SGPR operands of v_fmac). Same FMA order as v5/v6 -> bit-identical out.
#define DOT_S(ACC, XS)                                        \
    {                                                         \
        float* ap_ = (float*)&(ACC);                          \
        _Pragma("unroll")                                     \
        for (int c = 0; c < 4; ++c) {                         \
            float p0 = 0.f, p1 = 0.f;                         \
            _Pragma("unroll")                                 \
            for (int k = 0; k < 5; ++k) {                     \
                p0 = fmaf(m[c][k].x, (XS)[4 * k + 0], p0);    \
                p1 = fmaf(m[c][k].y, (XS)[4 * k + 1], p1);    \
                p0 = fmaf(m[c][k].z, (XS)[4 * k + 2], p0);    \
                p1 = fmaf(m[c][k].w, (XS)[4 * k + 3], p1);    \
            }                                                 \
            ap_[c] = fmaxf(p0 + p1, 0.f);                     \
        }                                                     \
    }

__global__ __launch_bounds__(NTHREADS, 4)
void attn_v8_kernel(const float* __restrict__ x,
                    const float* __restrict__ W3,
                    const float* __restrict__ W4,
                    const float* __restrict__ gamma,
                    float* __restrict__ out)
{
    const int t    = threadIdx.x;
    const int lane = t & 63;
    // Wave index, explicitly uniform -> x addressing provably scalar.
    const int wvu  = __builtin_amdgcn_readfirstlane(t >> 6);

    if (lane >= 50) return;           // no barrier in this kernel -> legal

    const float g   = gamma[0];
    const int   cf4 = lane;           // float4-column strip in [0,50)

    // Fused M = g*W3 + W4 for this thread's 4 columns, straight from global
    // (16 KB, L2-resident). 80 VGPRs, amortized over 32 rows.
    f32x4 m[4][5];
#pragma unroll
    for (int c = 0; c < 4; ++c) {
        const f32x4* a = (const f32x4*)(W3 + (4 * cf4 + c) * DICT);
        const f32x4* b = (const f32x4*)(W4 + (4 * cf4 + c) * DICT);
#pragma unroll
        for (int k = 0; k < 5; ++k) {
            f32x4 p = a[k], q = b[k], r;
            r.x = fmaf(g, p.x, q.x); r.y = fmaf(g, p.y, q.y);
            r.z = fmaf(g, p.z, q.z); r.w = fmaf(g, p.w, q.w);
            m[c][k] = r;
        }
    }

    const int row_base = blockIdx.x * ROWS_PER_BLOCK + wvu * ROWS_PER_WAVE;
    // Wave-uniform scalar view of this wave's 32 x rows (CK-style AS4 cast).
    kfloat* xc = (kfloat*)(size_t)(x + (size_t)row_base * DICT);
    f32x4*  op = (f32x4*)(out + (size_t)row_base * COLS) + cf4;  // 50 f4/row

    for (int r = 0; r < ROWS_PER_WAVE; r += 2) {
        // Two rows of x into SGPRs (compiler merges into s_load_dwordx8/x4;
        // both rows' loads issue back-to-back, one lgkm wait covers them).
        float xs0[DICT], xs1[DICT];
#pragma unroll
        for (int k = 0; k < DICT; ++k) xs0[k] = xc[r * DICT + k];
#pragma unroll
        for (int k = 0; k < DICT; ++k) xs1[k] = xc[(r + 1) * DICT + k];

        f32x4 acc0;
        DOT_S(acc0, xs0)
        __builtin_nontemporal_store(acc0, &op[(size_t)r * 50]);

        f32x4 acc1;
        DOT_S(acc1, xs1)
        __builtin_nontemporal_store(acc1, &op[(size_t)(r + 1) * 50]);
    }
}

extern "C" void kernel_launch(void* const* d_in, const int* in_sizes, int n_in,
                              void* d_out, int out_size, void* d_ws, size_t ws_size,
                              hipStream_t stream) {
    const float* x     = (const float*)d_in[0];
    // d_in[1] = W1, d_in[2] = W2 : mathematically unused (softmax over size-1 axis)
    const float* W3    = (const float*)d_in[3];
    const float* W4    = (const float*)d_in[4];
    const float* gamma = (const float*)d_in[5];
    float* out = (float*)d_out;

    attn_v8_kernel<<<NBLOCKS, NTHREADS, 0, stream>>>(x, W3, W4, gamma, out);
}